// Round 7
// baseline (335.849 us; speedup 1.0000x reference)
//
#include <hip/hip_runtime.h>
#include <cstdint>

// ---------------------------------------------------------------------------
// VAE attention block: GN -> QKV 1x1 conv -> softmax(QK^T) V -> proj + x
// B=4, H=W=64 (N=4096 pixels/batch), C=512, GROUPS=32
// R7: gemm_f8 restructured for the short-K regime (scores K=512):
//   - BK=256B (64 KB LDS, 2 blocks/CU): halves barrier/vmcnt-drain count
//   - 32B v8i fragment loads (2 contiguous ds_read_b128, no v_mov assembly);
//     XOR swizzle key must be EVEN (row&6) so 16B-chunk pairs keep canonical
//     order -- an odd key would permute K differently for A-row m vs B-row n
//   - truncating bf16 repack in the scores epilogue (p tolerates 2^-8)
//   - softmax divide deferred to proj (row scaling commutes through the
//     per-row linear conv): PV stores raw p.v; proj multiplies by rcp(l)
// ---------------------------------------------------------------------------

typedef __bf16 bf16_t;
typedef bf16_t bf16x8 __attribute__((ext_vector_type(8)));
typedef float floatx4 __attribute__((ext_vector_type(4)));
typedef int v8i __attribute__((ext_vector_type(8)));

__device__ __forceinline__ uint16_t f2b(float f) {
    uint32_t u = __builtin_bit_cast(uint32_t, f);
    u += 0x7fffu + ((u >> 16) & 1u);
    return (uint16_t)(u >> 16);
}
__device__ __forceinline__ float b2f(uint16_t h) {
    uint32_t u = ((uint32_t)h) << 16;
    return __builtin_bit_cast(float, u);
}
// pack 4 floats -> 4 fp8 e4m3 bytes
__device__ __forceinline__ unsigned pk_fp8x4(float a, float b, float c, float d) {
    int w = __builtin_amdgcn_cvt_pk_fp8_f32(a, b, 0, false);
    w = __builtin_amdgcn_cvt_pk_fp8_f32(c, d, w, true);
    return (unsigned)w;
}

__device__ __forceinline__ void lds_copy16(void* lds, const void* glob) {
    __builtin_amdgcn_global_load_lds(
        (__attribute__((address_space(1))) void*)(void*)glob,
        (__attribute__((address_space(3))) void*)lds,
        16, 0, 0);
}

// ---------------------------------------------------------------------------
// GroupNorm stats: one block per (batch, group). Also zeroes the row-sum
// buffer (harness re-poisons workspace before every launch).
// ---------------------------------------------------------------------------
__global__ __launch_bounds__(256) void gn_stats(const float* __restrict__ x,
                                                float* __restrict__ stats,
                                                float* __restrict__ lrow) {
    const int bg = blockIdx.x;            // 0..127
    const int tid = threadIdx.x;
    if (tid < 128) lrow[bg * 128 + tid] = 0.f;   // 128*128 = 16384 rows
    const int b = bg >> 5, g = bg & 31;
    const float* base = x + (long)b * (4096L * 512) + g * 16;
    float s = 0.f, sq = 0.f;
    #pragma unroll 8
    for (int i = 0; i < 64; i++) {
        int idx4 = tid + i * 256;          // float4 index within group
        int pixel = idx4 >> 2, c4 = idx4 & 3;
        const float4 v = *(const float4*)(base + (long)pixel * 512 + c4 * 4);
        s += v.x + v.y + v.z + v.w;
        sq += v.x * v.x + v.y * v.y + v.z * v.z + v.w * v.w;
    }
    #pragma unroll
    for (int off = 32; off > 0; off >>= 1) {
        s += __shfl_down(s, off);
        sq += __shfl_down(sq, off);
    }
    __shared__ float rs[4], rq[4];
    const int lane = tid & 63, w = tid >> 6;
    if (lane == 0) { rs[w] = s; rq[w] = sq; }
    __syncthreads();
    if (tid == 0) {
        float S = rs[0] + rs[1] + rs[2] + rs[3];
        float Q = rq[0] + rq[1] + rq[2] + rq[3];
        float mean = S * (1.f / 65536.f);
        float var = Q * (1.f / 65536.f) - mean * mean;
        stats[bg * 2 + 0] = mean;
        stats[bg * 2 + 1] = rsqrtf(var + 1e-5f);
    }
}

// ---------------------------------------------------------------------------
// GroupNorm apply: h_bf16 = (x-mean)*rstd*gamma + beta.  4 elems/thread.
// ---------------------------------------------------------------------------
__global__ __launch_bounds__(256) void gn_apply(const float* __restrict__ x,
                                                const float* __restrict__ stats,
                                                const float* __restrict__ gamma,
                                                const float* __restrict__ beta,
                                                uint16_t* __restrict__ h) {
    const long idx4 = (long)blockIdx.x * 256 + threadIdx.x;   // 0..2097151
    const long e0 = idx4 * 4;
    const int c = (int)(e0 & 511);
    const int b = (int)(e0 >> 21);                            // 4096*512 = 2^21
    const float2 st = ((const float2*)stats)[b * 32 + (c >> 4)];
    const float4 v = ((const float4*)x)[idx4];
    const float4 gm = ((const float4*)gamma)[c >> 2];
    const float4 bt = ((const float4*)beta)[c >> 2];
    union { ushort4 u; uint16_t s[4]; } o;
    o.s[0] = f2b((v.x - st.x) * st.y * gm.x + bt.x);
    o.s[1] = f2b((v.y - st.x) * st.y * gm.y + bt.y);
    o.s[2] = f2b((v.z - st.x) * st.y * gm.z + bt.z);
    o.s[3] = f2b((v.w - st.x) * st.y * gm.w + bt.w);
    ((ushort4*)h)[idx4] = o.u;
}

// ---------------------------------------------------------------------------
// Cast+transpose weights: wT[d][c] = bf16(w[c][d]), 512x512, 64x64 LDS tiles.
// ---------------------------------------------------------------------------
__global__ __launch_bounds__(256) void wcast_transpose(const float* __restrict__ w0,
                                                       const float* __restrict__ w1,
                                                       const float* __restrict__ w2,
                                                       const float* __restrict__ w3,
                                                       uint16_t* __restrict__ out) {
    const float* ws[4] = {w0, w1, w2, w3};
    const float* w = ws[blockIdx.z];
    uint16_t* o = out + (long)blockIdx.z * 512 * 512;
    __shared__ uint16_t t[64][65];
    const int nb = blockIdx.x * 64, kb = blockIdx.y * 64;
    const int lc = threadIdx.x & 63, lg = threadIdx.x >> 6;
    #pragma unroll
    for (int i = 0; i < 16; i++) {
        int r = lg * 16 + i;
        t[lc][r] = f2b(w[(long)(kb + r) * 512 + nb + lc]);   // t[n_loc][k_loc]
    }
    __syncthreads();
    #pragma unroll
    for (int i = 0; i < 16; i++) {
        int r = lg * 16 + i;
        o[(long)(nb + r) * 512 + kb + lc] = t[r][lc];        // wT[n][k]
    }
}

// ---------------------------------------------------------------------------
// Fused QKV GEMM (bf16 MFMA): [16384,512] x [1536,512]^T.  Grid (12, 128).
// Outputs fp8 e4m3: cols 0-511 -> q, 512-1023 -> k, 1024-1535 -> v stored
// TRANSPOSED (vt[b][ch][pix]).  No scale on q (applied in scores epilogue).
// ---------------------------------------------------------------------------
__global__ __launch_bounds__(256) void qkv_gemm(const uint16_t* __restrict__ h,
                                                const uint16_t* __restrict__ wT,
                                                const float* __restrict__ bq,
                                                const float* __restrict__ bk,
                                                const float* __restrict__ bv,
                                                uint8_t* __restrict__ q,
                                                uint8_t* __restrict__ k,
                                                uint8_t* __restrict__ vt) {
    __shared__ __align__(16) uint16_t smem[128 * 136];
    uint16_t* sA = smem;
    uint16_t* sB = smem + 8192;

    const int tid = threadIdx.x;
    const long m0 = (long)blockIdx.y * 128;
    const int n0 = blockIdx.x * 128;

    const int lane = tid & 63;
    const int wave = tid >> 6;
    const int wm = (wave & 1) * 64;
    const int wn = (wave >> 1) * 64;
    const int fr = lane & 15;
    const int fh = lane >> 4;
    const int sw = fr & 7;

    floatx4 acc[4][4];
    #pragma unroll
    for (int i = 0; i < 4; i++)
        #pragma unroll
        for (int j = 0; j < 4; j++) acc[i][j] = (floatx4){0.f, 0.f, 0.f, 0.f};

    for (int kt = 0; kt < 512; kt += 64) {
        __syncthreads();
        #pragma unroll
        for (int i = 0; i < 4; i++) {
            const int c = i * 256 + tid;
            const int row = c >> 3;
            const int gj = (c & 7) ^ (row & 7);
            lds_copy16(&sA[c * 8], h + (m0 + row) * 512L + kt + gj * 8);
            lds_copy16(&sB[c * 8], wT + (n0 + row) * 512L + kt + gj * 8);
        }
        __syncthreads();
        #pragma unroll
        for (int kk = 0; kk < 64; kk += 32) {
            const int jx = ((fh + (kk >> 3)) ^ sw) * 8;
            bf16x8 av[4], bv_[4];
            #pragma unroll
            for (int mi = 0; mi < 4; mi++)
                av[mi] = *(const bf16x8*)&sA[(wm + mi * 16 + fr) * 64 + jx];
            #pragma unroll
            for (int ni = 0; ni < 4; ni++)
                bv_[ni] = *(const bf16x8*)&sB[(wn + ni * 16 + fr) * 64 + jx];
            #pragma unroll
            for (int mi = 0; mi < 4; mi++)
                #pragma unroll
                for (int ni = 0; ni < 4; ni++)
                    acc[mi][ni] = __builtin_amdgcn_mfma_f32_16x16x32_bf16(
                        av[mi], bv_[ni], acc[mi][ni], 0, 0, 0);
        }
    }

    const int quad = lane >> 4;
    const int w = n0 >> 9;          // 0=q, 1=k, 2=v(T)
    const int nc = n0 & 511;
    const float* bias = (w == 0) ? bq : (w == 1) ? bk : bv;
    __syncthreads();
    if (w < 2) {
        #pragma unroll
        for (int ni = 0; ni < 4; ni++) {
            const int col_l = wn + ni * 16 + fr;
            const float bb = bias[nc + col_l];
            #pragma unroll
            for (int mi = 0; mi < 4; mi++) {
                #pragma unroll
                for (int r = 0; r < 4; r++) {
                    const int row_l = wm + mi * 16 + quad * 4 + r;
                    smem[row_l * 136 + col_l] = f2b(acc[mi][ni][r] + bb);
                }
            }
        }
        __syncthreads();
        uint8_t* out = (w == 0) ? q : k;
        #pragma unroll
        for (int it = 0; it < 8; it++) {
            const int row_l = it * 16 + (tid >> 4);
            const int c0 = (tid & 15) * 8;
            const uint4 d = *(const uint4*)&smem[row_l * 136 + c0];
            const uint16_t* e = (const uint16_t*)&d;
            uint2 o;
            o.x = pk_fp8x4(b2f(e[0]), b2f(e[1]), b2f(e[2]), b2f(e[3]));
            o.y = pk_fp8x4(b2f(e[4]), b2f(e[5]), b2f(e[6]), b2f(e[7]));
            *(uint2*)&out[(m0 + row_l) * 512 + nc + c0] = o;
        }
    } else {
        // transposed fp8 repack: s8[ch][pix], byte stride 144 (16B-aligned)
        uint8_t* s8 = (uint8_t*)smem;
        #pragma unroll
        for (int ni = 0; ni < 4; ni++) {
            const int ch_l = wn + ni * 16 + fr;
            const float bb = bias[nc + ch_l];
            #pragma unroll
            for (int mi = 0; mi < 4; mi++) {
                const int pix0 = wm + mi * 16 + quad * 4;
                *(unsigned*)&s8[ch_l * 144 + pix0] =
                    pk_fp8x4(acc[mi][ni][0] + bb, acc[mi][ni][1] + bb,
                             acc[mi][ni][2] + bb, acc[mi][ni][3] + bb);
            }
        }
        __syncthreads();
        const long b = m0 >> 12;
        const int pixb = (int)(m0 & 4095);
        uint8_t* vtb = vt + b * (512L * 4096);
        #pragma unroll
        for (int it = 0; it < 4; it++) {
            const int ch_l = it * 32 + (tid >> 3);
            const int p0 = (tid & 7) * 16;
            *(uint4*)&vtb[(long)(nc + ch_l) * 4096 + pixb + p0] =
                *(const uint4*)&s8[ch_l * 144 + p0];
        }
    }
}

// ---------------------------------------------------------------------------
// fp8 MFMA GEMM (MX-scaled, unit scales): C = A . B^T, A/B fp8 e4m3, K contig.
// 128x128 tile, BK=256 bytes (64 KB LDS, 2 blocks/CU), 32B v8i fragment loads
// with EVEN XOR swizzle (row&6) -- preserves 16B-pair order so both operands
// see canonical K.
// MODE 3 (scores): p = exp2(acc*scale) -> truncated-bf16 repack -> fp8 out +
//                  fp32 row-sum atomics into lrow.
// MODE 4 (PV):     raw acc -> bf16 out (softmax divide deferred to proj).
// ---------------------------------------------------------------------------
template <int MODE>
__global__ __launch_bounds__(256) void gemm_f8(const uint8_t* __restrict__ A,
                                               const uint8_t* __restrict__ B,
                                               void* __restrict__ Cout,
                                               float* __restrict__ lrow,
                                               float scale, int M, int N, int K,
                                               long aStride, long bStride, long cStride) {
    __shared__ __align__(32) uint8_t smem8[65536];   // sA 32 KB | sB 32 KB
    uint8_t* sA = smem8;
    uint8_t* sB = smem8 + 32768;
    uint16_t* tile = (uint16_t*)smem8;               // epilogue reuse, stride 136

    const int tid = threadIdx.x;
    const int bz = blockIdx.z;
    const long m0 = (long)blockIdx.y * 128;
    const long n0 = (long)blockIdx.x * 128;
    const uint8_t* Ab = A + (long)bz * aStride;
    const uint8_t* Bb = B + (long)bz * bStride;

    const int lane = tid & 63;
    const int wave = tid >> 6;
    const int wm = (wave & 1) * 64;
    const int wn = (wave >> 1) * 64;
    const int fr = lane & 15;
    const int quad = lane >> 4;

    floatx4 acc[4][4];
    #pragma unroll
    for (int i = 0; i < 4; i++)
        #pragma unroll
        for (int j = 0; j < 4; j++) acc[i][j] = (floatx4){0.f, 0.f, 0.f, 0.f};

    const int pj = (quad ^ ((fr >> 1) & 3)) * 32;   // 32B pair offset (even swizzle)

    for (int kt = 0; kt < K; kt += 256) {
        __syncthreads();
        #pragma unroll
        for (int i = 0; i < 8; i++) {
            const int c = i * 256 + tid;             // 2048 chunks per matrix
            const int row = c >> 4;                  // 16 chunks of 16B per row
            const int gj = (c & 15) ^ (row & 6);     // even key: pair order kept
            lds_copy16(&sA[c * 16], Ab + (m0 + row) * (long)K + kt + gj * 16);
            lds_copy16(&sB[c * 16], Bb + (n0 + row) * (long)K + kt + gj * 16);
        }
        __syncthreads();
        #pragma unroll
        for (int ks = 0; ks < 2; ks++) {
            v8i af[4], bf[4];
            #pragma unroll
            for (int mi = 0; mi < 4; mi++)
                af[mi] = *(const v8i*)&sA[(wm + mi * 16 + fr) * 256 + ks * 128 + pj];
            #pragma unroll
            for (int ni = 0; ni < 4; ni++)
                bf[ni] = *(const v8i*)&sB[(wn + ni * 16 + fr) * 256 + ks * 128 + pj];
            #pragma unroll
            for (int mi = 0; mi < 4; mi++)
                #pragma unroll
                for (int ni = 0; ni < 4; ni++)
                    acc[mi][ni] = __builtin_amdgcn_mfma_scale_f32_16x16x128_f8f6f4(
                        af[mi], bf[ni], acc[mi][ni], 0, 0,
                        0, 0x7f7f7f7fu, 0, 0x7f7f7f7fu);
        }
    }

    __syncthreads();
    // repack to bf16 tile (stride 136).  MODE 3: exp2 + TRUNCATED bf16 (cheap,
    // p tolerates 2^-8 rel).  MODE 4: RNE bf16 (feeds proj GEMM).
    #pragma unroll
    for (int ni = 0; ni < 4; ni++) {
        const int col_l = wn + ni * 16 + fr;
        #pragma unroll
        for (int mi = 0; mi < 4; mi++) {
            #pragma unroll
            for (int r = 0; r < 4; r++) {
                const int row_l = wm + mi * 16 + quad * 4 + r;
                float v = acc[mi][ni][r];
                if (MODE == 3) {
                    v = exp2f(v * scale);
                    tile[row_l * 136 + col_l] =
                        (uint16_t)(__builtin_bit_cast(uint32_t, v) >> 16);
                } else {
                    tile[row_l * 136 + col_l] = f2b(v);
                }
            }
        }
    }
    __syncthreads();
    if (MODE == 3) {
        uint8_t* Cb = (uint8_t*)Cout + (long)bz * cStride;
        float* lb = lrow + (long)bz * M;
        #pragma unroll
        for (int it = 0; it < 8; it++) {
            const int row_l = it * 16 + (tid >> 4);
            const int c0 = (tid & 15) * 8;
            const uint4 d = *(const uint4*)&tile[row_l * 136 + c0];
            const uint16_t* e = (const uint16_t*)&d;
            float f[8];
            float ps = 0.f;
            #pragma unroll
            for (int j = 0; j < 8; j++) { f[j] = b2f(e[j]); ps += f[j]; }
            uint2 o;
            o.x = pk_fp8x4(f[0], f[1], f[2], f[3]);
            o.y = pk_fp8x4(f[4], f[5], f[6], f[7]);
            *(uint2*)&Cb[(m0 + row_l) * (long)N + n0 + c0] = o;
            #pragma unroll
            for (int off = 1; off < 16; off <<= 1) ps += __shfl_xor(ps, off);
            if ((tid & 15) == 0) atomicAdd(&lb[m0 + row_l], ps);
        }
    } else {
        uint16_t* Cb = (uint16_t*)Cout + (long)bz * cStride;
        #pragma unroll
        for (int it = 0; it < 8; it++) {
            const int row_l = it * 16 + (tid >> 4);
            const int c0 = (tid & 15) * 8;
            *(uint4*)&Cb[(m0 + row_l) * (long)N + n0 + c0] =
                *(const uint4*)&tile[row_l * 136 + c0];
        }
    }
}

// ---------------------------------------------------------------------------
// Projection GEMM (bf16 MFMA): out = x + (ao_un @ wp^T + bp per-row-scaled):
// out[m][n] = acc[m][n] * (1/l[m]) + bp[n] + x[m][n]
// (softmax divide commutes through the per-row linear conv)
// ---------------------------------------------------------------------------
__global__ __launch_bounds__(256) void gemm_proj(const uint16_t* __restrict__ A,
                                                 const uint16_t* __restrict__ B,
                                                 float* __restrict__ Cout,
                                                 const float* __restrict__ bias,
                                                 const float* __restrict__ resid,
                                                 const float* __restrict__ lrow) {
    __shared__ __align__(16) uint16_t smem[128 * 136];
    __shared__ float lbuf[128];
    uint16_t* sA = smem;
    uint16_t* sB = smem + 8192;
    const int N = 512;

    const int tid = threadIdx.x;
    const long m0 = (long)blockIdx.y * 128;
    const long n0 = (long)blockIdx.x * 128;

    if (tid < 128) lbuf[tid] = lrow[m0 + tid];

    const int lane = tid & 63;
    const int wave = tid >> 6;
    const int wm = (wave & 1) * 64;
    const int wn = (wave >> 1) * 64;
    const int fr = lane & 15;
    const int fh = lane >> 4;
    const int sw = fr & 7;

    floatx4 acc[4][4];
    #pragma unroll
    for (int i = 0; i < 4; i++)
        #pragma unroll
        for (int j = 0; j < 4; j++) acc[i][j] = (floatx4){0.f, 0.f, 0.f, 0.f};

    for (int kt = 0; kt < 512; kt += 64) {
        __syncthreads();
        #pragma unroll
        for (int i = 0; i < 4; i++) {
            const int c = i * 256 + tid;
            const int row = c >> 3;
            const int gj = (c & 7) ^ (row & 7);
            lds_copy16(&sA[c * 8], A + (m0 + row) * 512L + kt + gj * 8);
            lds_copy16(&sB[c * 8], B + (n0 + row) * 512L + kt + gj * 8);
        }
        __syncthreads();
        #pragma unroll
        for (int kk = 0; kk < 64; kk += 32) {
            const int jx = ((fh + (kk >> 3)) ^ sw) * 8;
            bf16x8 av[4], bv[4];
            #pragma unroll
            for (int mi = 0; mi < 4; mi++)
                av[mi] = *(const bf16x8*)&sA[(wm + mi * 16 + fr) * 64 + jx];
            #pragma unroll
            for (int ni = 0; ni < 4; ni++)
                bv[ni] = *(const bf16x8*)&sB[(wn + ni * 16 + fr) * 64 + jx];
            #pragma unroll
            for (int mi = 0; mi < 4; mi++)
                #pragma unroll
                for (int ni = 0; ni < 4; ni++)
                    acc[mi][ni] = __builtin_amdgcn_mfma_f32_16x16x32_bf16(
                        av[mi], bv[ni], acc[mi][ni], 0, 0, 0);
        }
    }

    const int quad = lane >> 4;
    #pragma unroll
    for (int ni = 0; ni < 4; ni++) {
        const long col = n0 + wn + ni * 16 + fr;
        const float bv_ = bias[col];
        #pragma unroll
        for (int mi = 0; mi < 4; mi++) {
            #pragma unroll
            for (int r = 0; r < 4; r++) {
                const int rl = wm + mi * 16 + quad * 4 + r;
                const long row = m0 + rl;
                const float inv = __builtin_amdgcn_rcpf(lbuf[rl]);
                Cout[row * N + col] = acc[mi][ni][r] * inv + bv_ + resid[row * N + col];
            }
        }
    }
}

// ---------------------------------------------------------------------------
extern "C" void kernel_launch(void* const* d_in, const int* in_sizes, int n_in,
                              void* d_out, int out_size, void* d_ws, size_t ws_size,
                              hipStream_t stream) {
    const float* x  = (const float*)d_in[0];
    const float* gg = (const float*)d_in[1];
    const float* gb = (const float*)d_in[2];
    const float* wq = (const float*)d_in[3];
    const float* bq = (const float*)d_in[4];
    const float* wk = (const float*)d_in[5];
    const float* bk = (const float*)d_in[6];
    const float* wv = (const float*)d_in[7];
    const float* bv = (const float*)d_in[8];
    const float* wp = (const float*)d_in[9];
    const float* bp = (const float*)d_in[10];
    float* out = (float*)d_out;

    char* ws = (char*)d_ws;
    size_t off = 0;
    auto alloc = [&](size_t bytes) {
        char* p = ws + off;
        off += (bytes + 255) & ~(size_t)255;
        return p;
    };
    float*    stats = (float*)alloc(128 * 2 * sizeof(float));
    float*    lrow  = (float*)alloc(16384L * 4);
    uint16_t* h     = (uint16_t*)alloc(16384L * 512 * 2);
    uint16_t* wT    = (uint16_t*)alloc(4L * 512 * 512 * 2);
    uint8_t*  q8    = (uint8_t*)alloc(16384L * 512);
    uint8_t*  k8    = (uint8_t*)alloc(16384L * 512);
    uint8_t*  vt8   = (uint8_t*)alloc(16384L * 512);
    uint8_t*  sc8   = (uint8_t*)alloc(4L * 4096 * 4096);
    uint16_t* ao    = (uint16_t*)alloc(16384L * 512 * 2);
    if (off > ws_size) return;  // workspace too small -> fail visibly

    gn_stats<<<128, 256, 0, stream>>>(x, stats, lrow);
    gn_apply<<<8192, 256, 0, stream>>>(x, stats, gg, gb, h);
    wcast_transpose<<<dim3(8, 8, 4), 256, 0, stream>>>(wq, wk, wv, wp, wT);

    // q / k / v^T (fp8) in one dispatch
    qkv_gemm<<<dim3(12, 128), 256, 0, stream>>>(h, wT, bq, bk, bv, q8, k8, vt8);
    // p[b] = exp2(scale * q[b] @ k[b]^T) as fp8, row sums into lrow
    const float qscale = 0.06375871540654937f;   // log2(e)/sqrt(512)
    gemm_f8<3><<<dim3(32, 32, 4), 256, 0, stream>>>(q8, k8, sc8, lrow, qscale,
                                                    4096, 4096, 512,
                                                    4096L * 512, 4096L * 512, 4096L * 4096);
    // ao_un[b] = p[b] @ v[b]   (divide deferred to proj)
    gemm_f8<4><<<dim3(4, 32, 4), 256, 0, stream>>>(sc8, vt8, ao, lrow, 1.f,
                                                   4096, 512, 4096,
                                                   4096L * 4096, 512L * 4096, 4096L * 512);
    // out = x + (ao_un @ wp^T)/l + bp
    gemm_proj<<<dim3(4, 128), 256, 0, stream>>>(ao, wT + 3 * 262144, out, bp, x, lrow);
}